// Round 8
// baseline (604.186 us; speedup 1.0000x reference)
//
#include <hip/hip_runtime.h>
#include <math.h>

#ifndef M_PI
#define M_PI 3.14159265358979323846
#endif

// ---------------- architecture constants ----------------
#define BLOCK 256
#define BPTS  64            // points per block
#define DIM   136           // hidden width = 8*(1+2*8)
#define WMAT  (DIM*DIM)     // 18496 elements per weight matrix
#define NTILE 9             // ceil(136/16) N tiles
#define KS    5             // ceil(136/32) K steps
#define FRAGB 1024          // bytes per staged MFMA B-fragment (64 lanes x 16B)
#define MATB  (NTILE*KS*FRAGB) // 46080 B per staged matrix
#define TMASK 524287u       // T-1, T = 2^19
#define LVLSTRIDE 4194304   // T*F floats per level
#define OUTW  139           // 3 + 136 output floats per point
#define I2P   0.15915494309189535f

typedef _Float16 half8v __attribute__((ext_vector_type(8)));
typedef float    f32x4  __attribute__((ext_vector_type(4)));

struct FfbConsts { float freqs[8]; int res[7]; };

__device__ __forceinline__ float fract_(float x){ return x - floorf(x); } // v_fract
__device__ __forceinline__ float sin_rev(float r){
#if __has_builtin(__builtin_amdgcn_sinf)
    return __builtin_amdgcn_sinf(r);
#else
    return sinf(r * 6.283185307179586f);
#endif
}

// ---- fallback B-fragment from fp32 weights (only if ws too small) ----
__device__ __forceinline__ half8v bfrag_f32(const float* __restrict__ mat,
                                            int ntile, int ks, int rr, int kg){
    int row = ntile*16 + rr;
    int k0  = ks*32 + kg*8;
    half8v h = {};
    if (row < DIM){
        #pragma unroll
        for (int j=0;j<8;++j){
            int k = k0+j;
            if (k < DIM) h[j] = (_Float16)mat[row*DIM+k];
        }
    }
    return h;
}

// ---- MFMA GEMM with STREAMED B (double-buffered, 1-step prefetch) ----
// C[64x(136+pad)] = src[64x136] * W^T; A from LDS, B streamed global->VGPR.
__device__ __forceinline__ void gemm_stream(const _Float16* __restrict__ src,
                                            const char* __restrict__ stg,
                                            const float* __restrict__ f32m,
                                            int use16, int n0, int nt,
                                            int lane16, int wm, int rr, int kg,
                                            f32x4 acc[2][5])
{
    #pragma unroll
    for (int mi=0; mi<2; ++mi)
        #pragma unroll
        for (int ni=0; ni<5; ++ni)
            acc[mi][ni] = (f32x4){0.f,0.f,0.f,0.f};

    const _Float16* a0p = src + (size_t)(wm*32 + rr) * DIM;
    half8v bb0[5], bb1[5];

    #pragma unroll
    for (int ni=0; ni<5; ++ni)
        if (ni < nt)
            bb0[ni] = use16
                ? *(const half8v*)(stg + (size_t)(((n0+ni)*KS + 0)*FRAGB) + lane16)
                : bfrag_f32(f32m, n0+ni, 0, rr, kg);

    #pragma unroll
    for (int ks=0; ks<KS; ++ks){
        half8v* bc = (ks & 1) ? bb1 : bb0;   // static after unroll (no scratch)
        half8v* bn = (ks & 1) ? bb0 : bb1;
        if (ks < KS-1){
            #pragma unroll
            for (int ni=0; ni<5; ++ni)
                if (ni < nt)
                    bn[ni] = use16
                        ? *(const half8v*)(stg + (size_t)(((n0+ni)*KS + ks+1)*FRAGB) + lane16)
                        : bfrag_f32(f32m, n0+ni, ks+1, rr, kg);
        }
        const bool av  = (ks < 4) || (kg == 0);   // A tail mask (136 = 4*32 + 8)
        const int koff = ks*32 + kg*8;
        half8v a0 = {}, a1 = {};
        if (av){
            a0 = *(const half8v*)(a0p + koff);
            a1 = *(const half8v*)(a0p + 16*DIM + koff);
        }
        #pragma unroll
        for (int ni=0; ni<5; ++ni)
            if (ni < nt){
                acc[0][ni] = __builtin_amdgcn_mfma_f32_16x16x32_f16(a0, bc[ni], acc[0][ni], 0,0,0);
                acc[1][ni] = __builtin_amdgcn_mfma_f32_16x16x32_f16(a1, bc[ni], acc[1][ni], 0,0,0);
            }
    }
}

// ---- hash-grid: issue loads EARLY (one full layer ahead), finish later ----
__device__ __forceinline__ void grid_issue(const float* __restrict__ tables,
                                           int level, int res, int t,
                                           const float (*pin)[3],
                                           float w[2], float4 fa[2], float4 fb[2]){
    const int p = t >> 2, q = t & 3;
    const float resf = (float)res;
    float fr[3]; int ip[3];
    #pragma unroll
    for (int d=0; d<3; ++d){
        float xi  = (pin[p][d] + 1.0f) * 0.5f;
        float pos = xi * resf;
        float fl  = floorf(pos);
        fr[d] = pos - fl;
        ip[d] = (int)fl;
    }
    #pragma unroll
    for (int k=0; k<2; ++k){
        int cc = 2*q + k;
        int dx = (cc>>2)&1, dy = (cc>>1)&1, dz = cc&1;
        unsigned h = (unsigned)(ip[0]+dx)
                   ^ ((unsigned)(ip[1]+dy)*2654435761u)
                   ^ ((unsigned)(ip[2]+dz)*805459861u);
        unsigned idx = h & TMASK;
        const float* fp = tables + (size_t)level*LVLSTRIDE + (size_t)idx*8;
        fa[k] = *(const float4*)fp;
        fb[k] = *(const float4*)(fp+4);
        float wx = dx ? fr[0] : 1.0f-fr[0];
        float wy = dy ? fr[1] : 1.0f-fr[1];
        float wz = dz ? fr[2] : 1.0f-fr[2];
        w[k] = wx*wy*wz;
    }
}
__device__ __forceinline__ void grid_finish(int t, const float w[2],
                                            const float4 fa[2], const float4 fb[2],
                                            float (*vfeat)[8]){
    const int p = t >> 2, q = t & 3;
    float acc[8];
    #pragma unroll
    for (int j=0;j<8;++j) acc[j]=0.0f;
    #pragma unroll
    for (int k=0;k<2;++k){
        acc[0]=fmaf(w[k],fa[k].x,acc[0]); acc[1]=fmaf(w[k],fa[k].y,acc[1]);
        acc[2]=fmaf(w[k],fa[k].z,acc[2]); acc[3]=fmaf(w[k],fa[k].w,acc[3]);
        acc[4]=fmaf(w[k],fb[k].x,acc[4]); acc[5]=fmaf(w[k],fb[k].y,acc[5]);
        acc[6]=fmaf(w[k],fb[k].z,acc[6]); acc[7]=fmaf(w[k],fb[k].w,acc[7]);
    }
    #pragma unroll
    for (int j=0;j<8;++j){
        float v = acc[j];
        v += __shfl_xor(v, 1);
        v += __shfl_xor(v, 2);
        if (q == 0) vfeat[p][j] = v;
    }
}

// ---- pre-stage all 14 weight matrices as fp16 MFMA fragments (zero-padded) ----
__global__ void convert_weights(const float* __restrict__ ffW,
                                const float* __restrict__ oW,
                                _Float16* __restrict__ ws){
    int tid = blockIdx.x*blockDim.x + threadIdx.x;
    const int total = 14*NTILE*KS*64;
    if (tid >= total) return;
    int lane = tid & 63;
    int frag = (tid >> 6) % (NTILE*KS);
    int mat  = tid / ((NTILE*KS)*64);
    int nt = frag / KS, ks = frag % KS;
    int rr = lane & 15, kg = lane >> 4;
    int row = nt*16 + rr;
    int k0  = ks*32 + kg*8;
    const float* src = (mat < 7) ? ffW + (size_t)mat*WMAT : oW + (size_t)(mat-7)*WMAT;
    half8v h = {};
    if (row < DIM){
        #pragma unroll
        for (int j=0;j<8;++j){
            int k = k0 + j;
            if (k < DIM) h[j] = (_Float16)src[(size_t)row*DIM + k];
        }
    }
    *(half8v*)((char*)ws + (size_t)mat*MATB + (size_t)frag*FRAGB + lane*16) = h;
}

__global__ __launch_bounds__(BLOCK, 4)
void ffb_fused(const float* __restrict__ input, const float* __restrict__ tables,
               const float* __restrict__ W0,    const float* __restrict__ b0,
               const float* __restrict__ ffW,   const float* __restrict__ ffb,
               const float* __restrict__ oW,    const float* __restrict__ ob,
               const _Float16* __restrict__ w16, int use_ws,
               float* __restrict__ out, int npts, FfbConsts cst)
{
    __shared__ __align__(16) char smem[BPTS*OUTW*4];   // 35584 B: xbuf+embbuf / obuf union
    __shared__ __align__(16) float vfeat[BPTS][8];     // 2048 B
    __shared__ float pin[BPTS][3];                     // 768 B
    __shared__ float sfreq[8];

    _Float16* xbuf   = (_Float16*)smem;                // [64][136]
    _Float16* embbuf = xbuf + BPTS*DIM;                // [64][136]
    float*    obuf   = (float*)smem;                   // [64][139] (final phase)

    const int t    = threadIdx.x;
    const int lane = t & 63;
    const int rr   = lane & 15;
    const int kg   = lane >> 4;
    const int lane16 = lane * 16;
    const int wid  = t >> 6;
    const int wm   = wid >> 1;
    const int wn   = wid & 1;
    const int n0   = wn ? 4 : 0;
    const int nt   = wn ? 5 : 4;
    const int base = blockIdx.x * BPTS;
    const char* wsb = (const char*)w16;

    if (t < 8) sfreq[t] = cst.freqs[t];
    for (int i = t; i < BPTS*3; i += BLOCK){
        int gi = base*3 + i;
        pin[i/3][i%3] = (gi < npts*3) ? input[gi] : 0.0f;
    }
    __syncthreads();

    // ---- layer 0: x = sin(w0*(input@W0^T+b0)); w0/2pi = 32 exactly ----
    {
        const int p = t & 63;
        const int wu = __builtin_amdgcn_readfirstlane(t >> 6);
        float i0 = pin[p][0], i1 = pin[p][1], i2 = pin[p][2];
        #pragma unroll
        for (int j = 0; j < 34; ++j){
            int c = wu*34 + j;                       // wave-uniform -> scalar W0 loads
            float pre = W0[c*3]*i0 + W0[c*3+1]*i1 + W0[c*3+2]*i2 + b0[c];
            xbuf[p*DIM + c] = (_Float16)sin_rev(fract_(pre * 32.0f));
        }
    }

    // prefetch grid gathers for level 0 (consumed after layer 1's GEMM1)
    float gw[2]; float4 gfa[2], gfb[2];
    grid_issue(tables, 0, cst.res[0], t, pin, gw, gfa, gfb);
    __syncthreads();                                  // xbuf(layer0) ready

    float xout[2][5][4];
    #pragma unroll
    for (int mi=0; mi<2; ++mi)
        #pragma unroll
        for (int ni=0; ni<5; ++ni)
            #pragma unroll
            for (int r=0; r<4; ++r) xout[mi][ni][r] = 0.0f;

    #pragma unroll 1
    for (int l = 1; l <= 7; ++l){
        f32x4 acc[2][5];
        gemm_stream(xbuf, wsb + (size_t)(l-1)*MATB, ffW + (size_t)(l-1)*WMAT,
                    use_ws, n0, nt, lane16, wm, rr, kg, acc);
        __syncthreads();                              // (C) xbuf reads done

        grid_finish(t, gw, gfa, gfb, vfeat);          // consume level l-1 gathers
        if (l < 7)                                    // issue level l for NEXT layer:
            grid_issue(tables, l, cst.res[l], t, pin, gw, gfa, gfb);
            // loads stay in flight across epilogue+posenc+GEMM2+next GEMM1

        // ff epilogue: x <- sin(w0*(acc+b)) in-place; w0/2pi = 32
        {
            const float* bp = ffb + (size_t)(l-1)*DIM;
            #pragma unroll
            for (int ni=0; ni<5; ++ni)
                if (ni < nt){
                    int c = (n0+ni)*16 + rr;
                    if (c < DIM){
                        float bias = bp[c];
                        #pragma unroll
                        for (int mi=0; mi<2; ++mi)
                            #pragma unroll
                            for (int r=0; r<4; ++r){
                                int p = (wm*2+mi)*16 + kg*4 + r;
                                xbuf[p*DIM + c] =
                                    (_Float16)sin_rev(fract_((acc[mi][ni][r] + bias) * 32.0f));
                            }
                    }
                }
        }
        __syncthreads();                              // (D) xbuf new + vfeat ready

        // emb = posenc(v) + x : lane q of point p owns freqs {q, q+4}
        {
            const int p = t >> 2, q = t & 3;
            float vf[8];
            *(f32x4*)&vf[0] = *(const f32x4*)&vfeat[p][0];
            *(f32x4*)&vf[4] = *(const f32x4*)&vfeat[p][4];
            const float fA = sfreq[q]   * I2P;
            const float fB = sfreq[q+4] * I2P;
            _Float16* xb = xbuf   + p*DIM;
            _Float16* eb = embbuf + p*DIM;
            if (q == 0){
                #pragma unroll
                for (int c=0;c<8;++c) eb[c] = (_Float16)(vf[c] + (float)xb[c]);
            }
            #pragma unroll
            for (int fi=0; fi<8; ++fi){
                int cs = 8  + 8*fi + q;
                int cc = 72 + 8*fi + q;
                float rA = fract_(vf[fi]*fA);
                eb[cs]   = (_Float16)(sin_rev(rA) + (float)xb[cs]);
                eb[cc]   = (_Float16)(sin_rev(fract_(rA + 0.25f)) + (float)xb[cc]);
                float rB = fract_(vf[fi]*fB);
                eb[cs+4] = (_Float16)(sin_rev(rB) + (float)xb[cs+4]);
                eb[cc+4] = (_Float16)(sin_rev(fract_(rB + 0.25f)) + (float)xb[cc+4]);
            }
        }
        __syncthreads();                              // (E) embbuf ready

        gemm_stream(embbuf, wsb + (size_t)(7 + l-1)*MATB, oW + (size_t)(l-1)*WMAT,
                    use_ws, n0, nt, lane16, wm, rr, kg, acc);
        // out epilogue -> xout regs; 2*w0/2pi = 64
        {
            const float* bp = ob + (size_t)(l-1)*DIM;
            #pragma unroll
            for (int ni=0; ni<5; ++ni)
                if (ni < nt){
                    int c = (n0+ni)*16 + rr;
                    if (c < DIM){
                        float bias = bp[c];
                        #pragma unroll
                        for (int mi=0; mi<2; ++mi)
                            #pragma unroll
                            for (int r=0; r<4; ++r)
                                xout[mi][ni][r] +=
                                    sin_rev(fract_((acc[mi][ni][r] + bias) * 64.0f));
                    }
                }
        }
        // next iteration's GEMM1 reads xbuf (unchanged); first shared WRITE of next
        // iteration is behind (C)+(D) -> no extra barrier needed here (audited).
    }
    __syncthreads();                                  // all smem reads done -> obuf reuse

    // ---- final: assemble [xin(3), x_out/8] in LDS, then coalesced store ----
    if (t < BPTS){
        obuf[t*OUTW + 0] = (pin[t][0] + 1.0f) * 0.5f;
        obuf[t*OUTW + 1] = (pin[t][1] + 1.0f) * 0.5f;
        obuf[t*OUTW + 2] = (pin[t][2] + 1.0f) * 0.5f;
    }
    #pragma unroll
    for (int ni=0; ni<5; ++ni)
        if (ni < nt){
            int c = (n0+ni)*16 + rr;
            if (c < DIM){
                #pragma unroll
                for (int mi=0; mi<2; ++mi)
                    #pragma unroll
                    for (int r=0; r<4; ++r){
                        int p = (wm*2+mi)*16 + kg*4 + r;
                        obuf[p*OUTW + 3 + c] = xout[mi][ni][r] * 0.125f;
                    }
            }
        }
    __syncthreads();
    {
        const size_t gbase = (size_t)base * OUTW;
        const size_t gend  = (size_t)npts * OUTW;
        #pragma unroll 1
        for (int i = t; i < BPTS*OUTW; i += BLOCK){
            size_t g = gbase + (size_t)i;
            if (g < gend) out[g] = obuf[i];
        }
    }
}

extern "C" void kernel_launch(void* const* d_in, const int* in_sizes, int n_in,
                              void* d_out, int out_size, void* d_ws, size_t ws_size,
                              hipStream_t stream)
{
    const float* input  = (const float*)d_in[0];
    const float* tables = (const float*)d_in[1];
    const float* W0     = (const float*)d_in[2];
    const float* b0     = (const float*)d_in[3];
    const float* ffW    = (const float*)d_in[4];
    const float* ffb    = (const float*)d_in[5];
    const float* oW     = (const float*)d_in[6];
    const float* ob     = (const float*)d_in[7];
    float* out = (float*)d_out;
    const int npts = in_sizes[0] / 3;

    // Host-side constants: identical double-precision sequences to numpy.
    FfbConsts cst;
    {
        double b = exp((log(2048.0) - log(16.0)) / 7.0);
        for (int l = 0; l < 7; ++l)
            cst.res[l] = (int)floor(16.0 * pow(b, (double)l));
        double step = 19.0 / 7.0;
        for (int k = 0; k < 8; ++k){
            double e = (k == 7) ? 19.0 : step * (double)k;
            cst.freqs[k] = (float)pow(2.0, e);
        }
    }

    const size_t need = (size_t)14 * MATB;            // 645,120 B
    const int use_ws = (ws_size >= need) ? 1 : 0;
    _Float16* w16 = (_Float16*)d_ws;
    if (use_ws){
        const int total = 14*NTILE*KS*64;
        convert_weights<<<(total + BLOCK-1)/BLOCK, BLOCK, 0, stream>>>(ffW, oW, w16);
    }
    int nblk = (npts + BPTS - 1) / BPTS;
    ffb_fused<<<nblk, BLOCK, 0, stream>>>(input, tables, W0, b0, ffW, ffb, oW, ob,
                                          w16, use_ws, out, npts, cst);
}